// Round 5
// baseline (360.860 us; speedup 1.0000x reference)
//
#include <hip/hip_runtime.h>
#include <hip/hip_bf16.h>

typedef float f32x16 __attribute__((ext_vector_type(16)));
typedef unsigned char u8;
typedef unsigned int u32;
typedef unsigned long long u64;

#define NWG 512

// T=16, N=128, D=512, M=4096, TEMP=0.1. done is provably dead:
// positive_mask = block-diag(32-row trajectory groups) + eye, 31 positives/row.
// ws: zn8 fp8[4096*512] 2MiB | part f32[32][32][128] 512KB | possum f32[4096]
//     | wgsum f32[512] | ctr u32[16] (zeroed by hipMemsetAsync each launch)
// Single persistent kernel, 512 WGs co-resident (256 thr, 2 WG/CU), 3 grid
// barriers. Every ws slot is written before read => no other init needed.

__device__ inline void async_cp16(const u8* g, u8* l) {
    __builtin_amdgcn_global_load_lds(
        (const __attribute__((address_space(1))) unsigned int*)g,
        (__attribute__((address_space(3))) unsigned int*)l, 16, 0, 0);
}

__device__ inline void gridbar(u32* ctr, int ph) {
    __threadfence();
    __syncthreads();
    if (threadIdx.x == 0) {
        __hip_atomic_fetch_add(&ctr[ph], 1u, __ATOMIC_ACQ_REL, __HIP_MEMORY_SCOPE_AGENT);
        while (__hip_atomic_load(&ctr[ph], __ATOMIC_ACQUIRE, __HIP_MEMORY_SCOPE_AGENT) < NWG)
            __builtin_amdgcn_s_sleep(2);
    }
    __syncthreads();
    __threadfence();
}

__global__ __launch_bounds__(256, 2) void mega_kernel(
        const float* __restrict__ z, u8* __restrict__ zn8, float* __restrict__ part,
        float* __restrict__ possum, float* __restrict__ wgsum, u32* __restrict__ ctr,
        float* __restrict__ out) {
    __shared__ u8 Bt[2][32 * 512];        // 32 KB
    __shared__ float colred[4][4][32];    // 2 KB
    __shared__ float rowred[128];
    __shared__ float fred[8];
    __shared__ float red2[4];

    const int wg = blockIdx.x, tid = threadIdx.x;
    const int wave = tid >> 6, l = tid & 63;
    const int m = l & 31, h = l >> 5;

    // ---------------- phase 1: normalize rows 8wg..8wg+7 (half-wave per row)
    {
        int rl = tid >> 5, c = tid & 31;
        size_t R = (size_t)wg * 8 + rl;
        const float4* zr = (const float4*)(z + R * 512);
        float4 v[4];
        float ss = 0.f;
#pragma unroll
        for (int k = 0; k < 4; ++k) {
            v[k] = zr[c + 32 * k];
            ss += v[k].x * v[k].x + v[k].y * v[k].y + v[k].z * v[k].z + v[k].w * v[k].w;
        }
#pragma unroll
        for (int off = 16; off; off >>= 1) ss += __shfl_xor(ss, off, 64);
        float sc = 1.0f / fmaxf(sqrtf(ss), 1e-8f);
        u32* zw = (u32*)(zn8 + R * 512);
#pragma unroll
        for (int k = 0; k < 4; ++k) {
            u32 w = __builtin_amdgcn_cvt_pk_fp8_f32(v[k].x * sc, v[k].y * sc, 0, false);
            w = __builtin_amdgcn_cvt_pk_fp8_f32(v[k].z * sc, v[k].w * sc, w, true);
            zw[c + 32 * k] = w;
        }
    }
    gridbar(ctr, 0);

    // ---------------- phase 2: upper-tri 128x128 Gram tiles, fused exp epilogue
    for (int job = wg; job < 528; job += NWG) {
        int t = job, i = 0;
        while (t >= 32 - i) { t -= 32 - i; ++i; }
        int j = i + t;
        int rowbase = i * 128 + wave * 32;
        bool diagwg = (i == j);

        __syncthreads();              // Bt/LDS free from previous job

        long af[32];                  // A resident: 64 VGPRs, full K=512
        const u8* arow = zn8 + (size_t)(rowbase + m) * 512 + h * 8;
#pragma unroll
        for (int kc = 0; kc < 32; ++kc) af[kc] = *(const long*)(arow + kc * 16);

        float expacc[16];
#pragma unroll
        for (int r = 0; r < 16; ++r) expacc[r] = 0.f;

        {   // stage tile 0 (async, swizzled: slot g of col C holds granule g^(C&7))
            int colbase = j * 128;
#pragma unroll
            for (int it = 0; it < 4; ++it) {
                int c = wave * 8 + 2 * it;
                int C = colbase + c + h;
                async_cp16(zn8 + (size_t)C * 512 + (m ^ (C & 7)) * 16, &Bt[0][c * 512]);
            }
        }
        int sB16 = (m & 7) * 16;
        for (int ct = 0; ct < 4; ++ct) {
            __syncthreads();          // stage(ct) landed
            if (ct < 3) {
                int colbase = j * 128 + (ct + 1) * 32;
                u8* dstb = &Bt[(ct + 1) & 1][0];
#pragma unroll
                for (int it = 0; it < 4; ++it) {
                    int c = wave * 8 + 2 * it;
                    int C = colbase + c + h;
                    async_cp16(zn8 + (size_t)C * 512 + (m ^ (C & 7)) * 16, dstb + c * 512);
                }
            }
            const u8* bcol = &Bt[ct & 1][m * 512 + h * 8];
            f32x16 acc0 = {}, acc1 = {};   // 2 independent MFMA chains
#pragma unroll
            for (int kc = 0; kc < 16; ++kc) {
                u64 b0 = *(const u64*)(bcol + (((2 * kc) * 16) ^ sB16));
                u64 b1 = *(const u64*)(bcol + (((2 * kc + 1) * 16) ^ sB16));
                acc0 = __builtin_amdgcn_mfma_f32_32x32x16_fp8_fp8(af[2 * kc], (long)b0, acc0, 0, 0, 0);
                acc1 = __builtin_amdgcn_mfma_f32_32x32x16_fp8_fp8(af[2 * kc + 1], (long)b1, acc1, 0, 0, 0);
            }
            bool diagtile = diagwg && (ct == wave);
            float cs = 0.f;
#pragma unroll
            for (int r = 0; r < 16; ++r) {
                int rrow = (r & 3) + 8 * (r >> 2) + 4 * h;
                float e = (diagtile && rrow == m) ? 0.f : __expf((acc0[r] + acc1[r]) * 10.0f);
                expacc[r] += e;       // row sums
                cs += e;              // col m, this h-half's 16 rows
            }
            cs += __shfl_xor(cs, 32, 64);
            if (h == 0) colred[wave][ct][m] = cs;
        }
#pragma unroll
        for (int r = 0; r < 16; ++r) {
            float v = expacc[r];
            v += __shfl_xor(v, 1, 64);
            v += __shfl_xor(v, 2, 64);
            v += __shfl_xor(v, 4, 64);
            v += __shfl_xor(v, 8, 64);
            v += __shfl_xor(v, 16, 64);
            if (m == 0) rowred[wave * 32 + ((r & 3) + 8 * (r >> 2) + 4 * h)] = v;
        }
        __syncthreads();
        if (tid < 128) {
            part[(size_t)(i * 32 + j) * 128 + tid] = rowred[tid];
            if (!diagwg) {            // transpose contribution to block j
                int tt = tid >> 5, c2 = tid & 31;
                part[(size_t)(j * 32 + i) * 128 + tid] =
                    colred[0][tt][c2] + colred[1][tt][c2] +
                    colred[2][tt][c2] + colred[3][tt][c2];
            }
        }
    }
    // positives: WGs 384..415, one trajectory group per wave (A==B => Z Z^T)
    if (wg >= 384 && wg < 416) {
        int g = (wg - 384) * 4 + wave;
        int u = m;
        int grow = (u < 16) ? (g * 16 + u) : (2048 + g * 16 + (u - 16));
        const u64* src = (const u64*)(zn8 + (size_t)grow * 512);
        f32x16 acc = {};
#pragma unroll
        for (int kc = 0; kc < 32; ++kc) {
            u64 f = src[2 * kc + h];
            acc = __builtin_amdgcn_mfma_f32_32x32x16_fp8_fp8((long)f, (long)f, acc, 0, 0, 0);
        }
#pragma unroll
        for (int r = 0; r < 16; ++r) {
            int rrow = (r & 3) + 8 * (r >> 2) + 4 * h;
            float v = (rrow == u) ? 0.f : acc[r];
            v += __shfl_xor(v, 1, 64);
            v += __shfl_xor(v, 2, 64);
            v += __shfl_xor(v, 4, 64);
            v += __shfl_xor(v, 8, 64);
            v += __shfl_xor(v, 16, 64);
            if (u == 0) {
                int gr = (rrow < 16) ? (g * 16 + rrow) : (2048 + g * 16 + (rrow - 16));
                possum[gr] = v * 10.0f;
            }
        }
    }
    gridbar(ctr, 1);

    // ---------------- phase 3: loss partial over this WG's 8 rows
    {
        int rl = tid >> 5, c = tid & 31;
        int R = wg * 8 + rl;
        int b = R >> 7, rr = R & 127;
        float es = part[(size_t)(b * 32 + c) * 128 + rr];   // slot c of row R
#pragma unroll
        for (int off = 16; off; off >>= 1) es += __shfl_xor(es, off, 64);
        if (c == 0) fred[rl] = __logf(es) - possum[R] * (1.0f / 31.0f);
        __syncthreads();
        if (tid == 0) {
            float s = 0.f;
#pragma unroll
            for (int k = 0; k < 8; ++k) s += fred[k];
            wgsum[wg] = s;
        }
    }
    gridbar(ctr, 2);

    if (wg == 0) {
        float s = wgsum[tid] + wgsum[tid + 256];
#pragma unroll
        for (int off = 32; off; off >>= 1) s += __shfl_down(s, off, 64);
        if (l == 0) red2[wave] = s;
        __syncthreads();
        if (tid == 0)
            out[0] = (red2[0] + red2[1] + red2[2] + red2[3]) * (1.0f / 4096.0f);
    }
}

extern "C" void kernel_launch(void* const* d_in, const int* in_sizes, int n_in,
                              void* d_out, int out_size, void* d_ws, size_t ws_size,
                              hipStream_t stream) {
    const float* z = (const float*)d_in[0];
    u8* zn8 = (u8*)d_ws;
    float* part = (float*)((char*)d_ws + (2u << 20));
    float* possum = part + 32 * 32 * 128;
    float* wgsum = possum + 4096;
    u32* ctr = (u32*)(wgsum + NWG);
    float* out = (float*)d_out;

    hipMemsetAsync(ctr, 0, 64, stream);   // zero grid-barrier counters
    mega_kernel<<<NWG, 256, 0, stream>>>(z, zn8, part, possum, wgsum, ctr, out);
}